// Round 8
// baseline (161.526 us; speedup 1.0000x reference)
//
#include <hip/hip_runtime.h>
#include <hip/hip_fp16.h>

#define N_DET 128
#define N_T   2048
#define NPIX  65536   // 256*256
#define NBATCH 4
#define THREADS 512
#define PXT 2                  // pixels per thread
#define TPX (THREADS * PXT)    // 1024 px per tile
#define NTILE (NPIX / TPX)     // 64
#define CDET 16                // dets per block (8 chunks cover 128)
#define NCB (N_DET / CDET)     // 8
#define GR 2                   // det rows per stage phase (32 KB)
#define PHASES (CDET / GR)     // 8

typedef float f4_t __attribute__((ext_vector_type(4)));

// Kernel 1: transpose+pack sino (B, N_DET, N_T) fp32 -> ws (N_DET, N_T) of
// 8-byte records { s_t[b0..b3] } as 4 fp16. ws = 2 MB (L2-resident slice per
// XCD). Also zeroes out[] for kernel 2's atomic accumulation.
__global__ __launch_bounds__(256) void sino_pack_kernel(
    const float* __restrict__ sino, float2* __restrict__ ws,
    float* __restrict__ out) {
  const int idx = blockIdx.x * blockDim.x + threadIdx.x;  // idx = d*N_T + t
  const __half2 lo = __floats2half2_rn(
      __builtin_nontemporal_load(sino + 0 * N_DET * N_T + idx),
      __builtin_nontemporal_load(sino + 1 * N_DET * N_T + idx));
  const __half2 hi = __floats2half2_rn(
      __builtin_nontemporal_load(sino + 2 * N_DET * N_T + idx),
      __builtin_nontemporal_load(sino + 3 * N_DET * N_T + idx));
  union { struct { __half2 a, b; } h; float2 f; } u;
  u.h.a = lo;
  u.h.b = hi;
  ws[idx] = u.f;
  out[idx] = 0.0f;  // exact cover: 128*2048 == 4*65536
}

// Kernel 2: pinned-burst, phase-staged LDS gather.
// r7 finding: compiler SINKS reg-destined lut loads past the barrier into the
// compute loop (VGPR 52 vs 64 needed by the burst) -> queue depth ~2, 50 us.
// Fix: empty asm volatile consuming all 16 b128 results pins the burst (and
// its wait) BEFORE the barrier. Depth->time curve (16->42, 8->43, 2->61 us)
// says this is the controlling variable.
// r7 finding 2: WRITE_SIZE 32.77 MB == 8.4M atomic lane-ops x 4 B. Atomics
// are memory-side (XCD L2s non-coherent; no merge possible). Fix: 16 dets
// per block -> 4x fewer atomics (8.4 MB).
// Structure: 512 thr, 2 px/thread, 16 dets via 8 phases x 2 rows,
// double-buffered 2x32 KB LDS (64 KB -> 2 blocks/CU, 16 waves/CU). Phase
// p+1's 32 KB staged async (global_load_lds) before compute(p); the per-phase
// __syncthreads vmcnt-drain is exactly the stage fence (T14).
// b&7 -> XCD: det-chunk c pinned per XCD, so each XCD stages only its 256 KB
// ws slice (L2-hit after first touch).
__global__ __launch_bounds__(512, 4) void das_lds_kernel(
    const float* __restrict__ lut, const float2* __restrict__ ws,
    float* __restrict__ out) {
  __shared__ __align__(16) float2 sbuf[2][GR * N_T];  // 2 x 32 KB

  const int b = blockIdx.x;
  const int T = b >> 3;  // tile 0..63
  const int c = b & 7;   // det-chunk 0..7 (== XCD under round-robin dispatch)
  const int tid = threadIdx.x;

  // 1) lut burst: 2 px x 16 dets x 8 B = 16 independent b128.
  f4_t l[PXT][PHASES];
#pragma unroll
  for (int i = 0; i < PXT; ++i) {
    const size_t P = (size_t)T * TPX + i * THREADS + tid;
    const f4_t* lp =
        reinterpret_cast<const f4_t*>(lut + (P * N_DET + c * CDET) * 2);
#pragma unroll
    for (int j = 0; j < PHASES; ++j) l[i][j] = lp[j];
  }

  // 2) Stage phase 0 (rows c*16+0,1 of ws) into sbuf[0]: 32 KB, async.
  auto stage = [&](int p, int bf) {
    const char* src = reinterpret_cast<const char*>(ws) +
                      ((size_t)(c * CDET + GR * p) << 14);  // row * 16 KB
    char* dst = reinterpret_cast<char*>(&sbuf[bf][0]);
#pragma unroll
    for (int r = 0; r < 4; ++r) {
      __builtin_amdgcn_global_load_lds(
          (const __attribute__((address_space(1))) void*)(src + r * 8192 +
                                                          tid * 16),
          (__attribute__((address_space(3))) void*)(dst + r * 8192 + tid * 16),
          16, 0, 0);
    }
  };
  stage(0, 0);

  // 3) PIN the burst: forces all 16 b128 materialized HERE (waits lut loads;
  //    the 4 stage loads issued after may remain in flight). Without this the
  //    compiler sinks the loads to their uses and the queue depth collapses.
  asm volatile(""
               : "+v"(l[0][0]), "+v"(l[0][1]), "+v"(l[0][2]), "+v"(l[0][3]),
                 "+v"(l[0][4]), "+v"(l[0][5]), "+v"(l[0][6]), "+v"(l[0][7]),
                 "+v"(l[1][0]), "+v"(l[1][1]), "+v"(l[1][2]), "+v"(l[1][3]),
                 "+v"(l[1][4]), "+v"(l[1][5]), "+v"(l[1][6]), "+v"(l[1][7]));

  __syncthreads();  // sbuf[0] staged

  float4 acc[PXT];
#pragma unroll
  for (int i = 0; i < PXT; ++i) acc[i] = make_float4(0.f, 0.f, 0.f, 0.f);

#pragma unroll
  for (int p = 0; p < PHASES; ++p) {
    // Issue next phase's stage first (async; completes by next barrier).
    if (p + 1 < PHASES) stage(p + 1, (p + 1) & 1);

    // Apodization for this phase's 2 dets (wave-uniform).
    const int d0 = c * CDET + GR * p;
    const float apd0 =
        0.5f - 0.5f * cosf(6.28318530717958647692f * ((float)d0 / 127.0f));
    const float apd1 = 0.5f - 0.5f * cosf(6.28318530717958647692f *
                                          ((float)(d0 + 1) / 127.0f));

    const float2* sb = &sbuf[p & 1][0];
#pragma unroll
    for (int i = 0; i < PXT; ++i) {
      const f4_t lv = l[i][p];
#pragma unroll
      for (int r = 0; r < GR; ++r) {
        const float tof = r ? lv.z : lv.x;
        const float al  = r ? lv.w : lv.y;
        const float kf = floorf(tof);
        const bool valid = (kf >= 0.0f) && (kf < (float)(N_T - 1));
        const int k0 = (int)fminf(fmaxf(kf, 0.0f), (float)(N_T - 2));
        const float w = valid ? (r ? apd1 : apd0) : 0.0f;

        const float2 r0 = sb[r * N_T + k0];      // ds_read_b64: tap t
        const float2 r1 = sb[r * N_T + k0 + 1];  // ds_read_b64: tap t+1
        const __half2* h0 = reinterpret_cast<const __half2*>(&r0);
        const __half2* h1 = reinterpret_cast<const __half2*>(&r1);
        const float2 s0a = __half22float2(h0[0]);  // t:   b0,b1
        const float2 s0b = __half22float2(h0[1]);  // t:   b2,b3
        const float2 s1a = __half22float2(h1[0]);  // t+1: b0,b1
        const float2 s1b = __half22float2(h1[1]);  // t+1: b2,b3

        acc[i].x += w * (s0a.x + al * (s1a.x - s0a.x));
        acc[i].y += w * (s0a.y + al * (s1a.y - s0a.y));
        acc[i].z += w * (s0b.x + al * (s1b.x - s0b.x));
        acc[i].w += w * (s0b.y + al * (s1b.y - s0b.y));
      }
    }

    if (p + 1 < PHASES) __syncthreads();  // next buf staged; cur buf free
  }

  const float nrm = 1.0f / 63.5f;  // sum(apod) == 63.5 analytically
#pragma unroll
  for (int i = 0; i < PXT; ++i) {
    const int P = T * TPX + i * THREADS + tid;
    atomicAdd(out + 0 * NPIX + P, acc[i].x * nrm);
    atomicAdd(out + 1 * NPIX + P, acc[i].y * nrm);
    atomicAdd(out + 2 * NPIX + P, acc[i].z * nrm);
    atomicAdd(out + 3 * NPIX + P, acc[i].w * nrm);
  }
}

// Fallback (no workspace): direct fp32 gather from original layout.
__global__ __launch_bounds__(256) void das_fallback_kernel(
    const float* __restrict__ lut, const float* __restrict__ S,
    float* __restrict__ out) {
  const int lane = threadIdx.x & 63;
  const int p = blockIdx.x * 4 + (threadIdx.x >> 6);

  const float4 lv =
      reinterpret_cast<const float4*>(lut + (size_t)p * 2 * N_DET)[lane];

  float acc0 = 0.f, acc1 = 0.f, acc2 = 0.f, acc3 = 0.f;
  float wsum = 0.f;

#pragma unroll
  for (int j = 0; j < 2; ++j) {
    const int d = 2 * lane + j;
    const float tof = j ? lv.z : lv.x;
    const float a   = j ? lv.w : lv.y;
    const float kf = floorf(tof);
    const bool valid = (kf >= 0.0f) && (kf < (float)(N_T - 1));
    const float kcl = fminf(fmaxf(kf, 0.0f), (float)(N_T - 2));
    const int k0 = (int)kcl;
    const float apd =
        0.5f - 0.5f * cosf(6.28318530717958647692f *
                           (1.0f / (float)(N_DET - 1)) * (float)d);
    wsum += apd;
    const float w = valid ? apd : 0.0f;
    const float om = 1.0f - a;
    const float* row = S + (size_t)d * N_T + k0;
    acc0 += w * (om * row[0 * N_DET * N_T] + a * row[0 * N_DET * N_T + 1]);
    acc1 += w * (om * row[1 * N_DET * N_T] + a * row[1 * N_DET * N_T + 1]);
    acc2 += w * (om * row[2 * N_DET * N_T] + a * row[2 * N_DET * N_T + 1]);
    acc3 += w * (om * row[3 * N_DET * N_T] + a * row[3 * N_DET * N_T + 1]);
  }

#pragma unroll
  for (int off = 32; off > 0; off >>= 1) {
    acc0 += __shfl_xor(acc0, off);
    acc1 += __shfl_xor(acc1, off);
    acc2 += __shfl_xor(acc2, off);
    acc3 += __shfl_xor(acc3, off);
    wsum += __shfl_xor(wsum, off);
  }

  if (lane == 0) {
    const float inv = 1.0f / fmaxf(wsum, 1.17549435e-38f);
    out[0 * NPIX + p] = acc0 * inv;
    out[1 * NPIX + p] = acc1 * inv;
    out[2 * NPIX + p] = acc2 * inv;
    out[3 * NPIX + p] = acc3 * inv;
  }
}

extern "C" void kernel_launch(void* const* d_in, const int* in_sizes, int n_in,
                              void* d_out, int out_size, void* d_ws, size_t ws_size,
                              hipStream_t stream) {
  const float* sino = (const float*)d_in[0];  // (B,1,N_DET,N_T) fp32
  const float* lut  = (const float*)d_in[1];  // (NY,NX,N_DET,2) fp32
  float* out = (float*)d_out;                 // (B,1,NY,NX) fp32

  const size_t need = (size_t)N_DET * N_T * 8;  // 2 MB packed ws
  if (ws_size >= need) {
    float2* ws = (float2*)d_ws;
    sino_pack_kernel<<<(N_DET * N_T) / 256, 256, 0, stream>>>(sino, ws, out);
    das_lds_kernel<<<NTILE * NCB, THREADS, 0, stream>>>(lut, ws, out);
  } else {
    das_fallback_kernel<<<NPIX / 4, 256, 0, stream>>>(lut, sino, out);
  }
}